// Round 6
// baseline (204.504 us; speedup 1.0000x reference)
//
#include <hip/hip_runtime.h>
#include <hip/hip_fp16.h>
#include <cstddef>

#define NEG_SLOPE 0.2f
#define TILE 4096
#define CSR_CAP 6144   // fixed per-bucket capacity; mean ~4096, sigma ~64

typedef _Float16 h8 __attribute__((ext_vector_type(8)));
typedef _Float16 h4 __attribute__((ext_vector_type(4)));
typedef float f4 __attribute__((ext_vector_type(4)));

__device__ __forceinline__ float leaky(float x) { return x >= 0.f ? x : NEG_SLOPE * x; }

__device__ __forceinline__ int wave_iscan(int v, int lane) {
#pragma unroll
    for (int off = 1; off < 64; off <<= 1) {
        int t = __shfl_up(v, off);
        if (lane >= off) v += t;
    }
    return v;
}

// ---------------------------------------------------------------------------
// prep: zero bfill + one-time fp16 transpose of W1 (128x128) and W2 (128x64).
// ---------------------------------------------------------------------------
__global__ __launch_bounds__(256) void prep(
    const float* __restrict__ W1, const float* __restrict__ W2,
    _Float16* __restrict__ W1t, _Float16* __restrict__ W2t,
    int* __restrict__ bfill)
{
    const int b = blockIdx.x;
    const int tid = threadIdx.x;
    if (b == 0) bfill[tid] = 0;
    if (b < 8) {
        for (int i = b * 2048 + tid; i < (b + 1) * 2048; i += 256) {
            int n = i >> 7, k = i & 127;
            W1t[n * 128 + k] = (_Float16)W1[k * 128 + n];
        }
    } else {
        const int bb = b - 8;
        for (int i = bb * 2048 + tid; i < (bb + 1) * 2048; i += 256) {
            int n = i >> 7, k = i & 127;  // n in [0,64)
            W2t[n * 128 + k] = (_Float16)W2[k * 64 + n];
        }
    }
}

// ---------------------------------------------------------------------------
// FAT KERNEL: blocks [0, nblk_gemm) do the layer-1 MFMA GEMM (F=128);
// blocks [nblk_gemm, nblk_gemm+nbt) do bucket_scatter (LDS-sorted, coalesced
// staging writes). LDS overlaid via union.  (identical to round-1 @190.9)
// ---------------------------------------------------------------------------
__global__ __launch_bounds__(256) void gemm1_scatter(
    const float* __restrict__ x, const _Float16* __restrict__ Wg,
    const float* __restrict__ a_s, const float* __restrict__ a_d,
    _Float16* __restrict__ hh, float* __restrict__ alphaS, float* __restrict__ alphaD,
    int N, int nblk_gemm,
    const int* __restrict__ src, const int* __restrict__ dst,
    int* __restrict__ bfill, unsigned* __restrict__ staging, int cap, int E)
{
    constexpr int K = 128;
    constexpr int LDK = K + 8;
    constexpr int F = 128;
    constexpr int NT = F / 16;

    __shared__ union {
        struct { _Float16 As[64 * LDK]; _Float16 Wt[F * LDK]; } g;
        struct {
            int lcnt[256]; int loff[256]; int gbase[256]; int ws[4];
            unsigned pairs[TILE]; unsigned char bkt[TILE];
        } s;
    } u;

    const int tid = threadIdx.x;

    if (blockIdx.x < (unsigned)nblk_gemm) {
        // ================= GEMM path =================
        const int wave = tid >> 6;
        const int lane = tid & 63;
        const int q = lane >> 4;
        const int c = lane & 15;
        const int rowb = blockIdx.x * 64;

        for (int i = tid; i < 64 * (K / 4); i += 256) {
            int r = i >> 5, c4 = i & 31;
            int gr = rowb + r;
            float4 v = (gr < N) ? *(const float4*)(x + (size_t)gr * K + c4 * 4)
                                : make_float4(0.f, 0.f, 0.f, 0.f);
            h4 hv = { (_Float16)v.x, (_Float16)v.y, (_Float16)v.z, (_Float16)v.w };
            *(h4*)(u.g.As + r * LDK + c4 * 4) = hv;
        }
        for (int i = tid; i < F * (K / 8); i += 256) {
            int n = i >> 4, k8 = i & 15;
            *(h8*)(u.g.Wt + n * LDK + k8 * 8) = *(const h8*)(Wg + n * 128 + k8 * 8);
        }
        __syncthreads();

        f4 acc[NT];
#pragma unroll
        for (int nt = 0; nt < NT; nt++) acc[nt] = (f4)0.f;

        const _Float16* aw = u.g.As + (wave * 16 + c) * LDK + q * 8;
#pragma unroll
        for (int kt = 0; kt < 4; kt++) {
            h8 af = *(const h8*)(aw + kt * 32);
#pragma unroll
            for (int nt = 0; nt < NT; nt++) {
                h8 bf = *(const h8*)(u.g.Wt + (nt * 16 + c) * LDK + kt * 32 + q * 8);
                acc[nt] = __builtin_amdgcn_mfma_f32_16x16x32_f16(af, bf, acc[nt], 0, 0, 0);
            }
        }

        float asl[NT], adl[NT];
#pragma unroll
        for (int nt = 0; nt < NT; nt++) {
            asl[nt] = a_s[nt * 16 + c];
            adl[nt] = a_d[nt * 16 + c];
        }
        const int row0 = rowb + wave * 16 + q * 4;
#pragma unroll
        for (int r = 0; r < 4; r++) {
            int row = row0 + r;
            if (row < N) {
                float ps = 0.f, pd = 0.f;
#pragma unroll
                for (int nt = 0; nt < NT; nt++) {
                    float v = acc[nt][r];
                    hh[(size_t)row * F + nt * 16 + c] = (_Float16)v;
                    ps += v * asl[nt];
                    pd += v * adl[nt];
                }
#pragma unroll
                for (int off = 8; off >= 1; off >>= 1) {
                    ps += __shfl_down(ps, off, 16);
                    pd += __shfl_down(pd, off, 16);
                }
                if (c == 0) { alphaS[row] = ps; alphaD[row] = pd; }
            }
        }
    } else {
        // ================= bucket_scatter path =================
        const int base = (blockIdx.x - nblk_gemm) * TILE;
        const int vt = min(TILE, E - base);

        u.s.lcnt[tid] = 0;
        __syncthreads();

        int d[TILE / 256], s[TILE / 256], r[TILE / 256];
#pragma unroll
        for (int j = 0; j < TILE / 256; j++) {
            int idx = base + j * 256 + tid;
            if (idx < E) {
                d[j] = dst[idx]; s[j] = src[idx];
                r[j] = atomicAdd(&u.s.lcnt[d[j] >> 8], 1);
            } else d[j] = -1;
        }
        __syncthreads();
        {
            int lane = tid & 63, wid = tid >> 6;
            int v = u.s.lcnt[tid];
            int incl = wave_iscan(v, lane);
            if (lane == 63) u.s.ws[wid] = incl;
            __syncthreads();
            int woff = 0;
            for (int w = 0; w < wid; w++) woff += u.s.ws[w];
            u.s.loff[tid] = woff + incl - v;
        }
        __syncthreads();
        {
            int c = u.s.lcnt[tid];
            if (c > 0) u.s.gbase[tid] = tid * cap + atomicAdd(&bfill[tid], c);
        }
        __syncthreads();
#pragma unroll
        for (int j = 0; j < TILE / 256; j++) {
            if (d[j] >= 0) {
                int b = d[j] >> 8;
                int slot = u.s.loff[b] + r[j];
                u.s.pairs[slot] = ((unsigned)d[j] << 16) | (unsigned)s[j];
                u.s.bkt[slot] = (unsigned char)b;
            }
        }
        __syncthreads();
        for (int slot = tid; slot < vt; slot += 256) {
            int b = u.s.bkt[slot];
            staging[u.s.gbase[b] + (slot - u.s.loff[b])] = u.s.pairs[slot];
        }
    }
}

// ---------------------------------------------------------------------------
// bucket_to_csr + layer-1 edge weights: per bucket, node counts/scan -> gapped
// CSR; placement now also computes w1 = exp(leaky(aS1[s]+aD1[d])) per edge,
// stores {src, w} as int2, and accumulates per-node denominators via LDS
// float atomics -> denom1[]. Removes the aS gather + exp + denom reduce from
// agg1's per-edge critical path.
// ---------------------------------------------------------------------------
__global__ __launch_bounds__(512) void bucket_to_csr(
    const unsigned* __restrict__ staging, const int* __restrict__ bfill,
    int* __restrict__ row_start, int* __restrict__ row_end,
    int2* __restrict__ sw_sorted, float* __restrict__ denom1,
    const float* __restrict__ aS1, const float* __restrict__ aD1,
    int cap, int N)
{
    __shared__ unsigned lp[CSR_CAP];
    __shared__ int lcnt[256], loff[256], lfill[256];
    __shared__ float dsum[256];
    __shared__ int ws[4];
    const int tid = threadIdx.x;
    const int b = blockIdx.x;
    const int beg = b * cap;
    const int len = bfill[b];

    if (tid < 256) { lcnt[tid] = 0; dsum[tid] = 0.f; }
    __syncthreads();
    for (int p = tid; p < len; p += 512) {
        unsigned u = staging[beg + p];
        lp[p] = u;  // len <= cap <= CSR_CAP
        atomicAdd(&lcnt[(u >> 16) & 255], 1);
    }
    __syncthreads();
    {
        int lane = tid & 63, wid = tid >> 6;
        int v = 0, incl = 0;
        if (tid < 256) {
            v = lcnt[tid];
            incl = wave_iscan(v, lane);
            if (lane == 63) ws[wid] = incl;
        }
        __syncthreads();
        if (tid < 256) {
            int woff = 0;
            for (int w = 0; w < wid; w++) woff += ws[w];
            int excl = woff + incl - v;
            loff[tid] = excl;
            lfill[tid] = excl;
            int node = (b << 8) + tid;
            if (node < N) { row_start[node] = beg + excl; row_end[node] = beg + excl + v; }
        }
    }
    __syncthreads();
    for (int p = tid; p < len; p += 512) {
        unsigned u = lp[p];
        int node = (u >> 16) & 255;
        int s = (int)(u & 0xFFFFu);
        int pos = atomicAdd(&lfill[node], 1);
        float w = __expf(leaky(aS1[s] + aD1[(b << 8) + node]));
        sw_sorted[beg + pos] = make_int2(s, __float_as_int(w));
        atomicAdd(&dsum[node], w);
    }
    __syncthreads();
    if (tid < 256) {
        int node = (b << 8) + tid;
        if (node < N) denom1[node] = dsum[tid];
    }
}

// ---------------------------------------------------------------------------
// MFMA GEMM + fused alpha dots (layer 2, fp16 input, pre-transposed fp16 W).
// ---------------------------------------------------------------------------
template <int F, typename IT>
__global__ __launch_bounds__(256) void gemm_mfma(
    const IT* __restrict__ x, const _Float16* __restrict__ Wg,
    const float* __restrict__ a_s, const float* __restrict__ a_d,
    _Float16* __restrict__ hh, float* __restrict__ alphaS, float* __restrict__ alphaD,
    int N)
{
    constexpr int K = 128;
    constexpr int LDK = K + 8;
    constexpr int NT = F / 16;

    __shared__ _Float16 As[64 * LDK];
    __shared__ _Float16 Wt[F * LDK];

    const int tid = threadIdx.x;
    const int wave = tid >> 6;
    const int lane = tid & 63;
    const int q = lane >> 4;
    const int c = lane & 15;
    const int rowb = blockIdx.x * 64;

    if constexpr (sizeof(IT) == 4) {
        for (int i = tid; i < 64 * (K / 4); i += 256) {
            int r = i >> 5, c4 = i & 31;
            int gr = rowb + r;
            float4 v = (gr < N) ? *(const float4*)((const float*)x + (size_t)gr * K + c4 * 4)
                                : make_float4(0.f, 0.f, 0.f, 0.f);
            h4 hv = { (_Float16)v.x, (_Float16)v.y, (_Float16)v.z, (_Float16)v.w };
            *(h4*)(As + r * LDK + c4 * 4) = hv;
        }
    } else {
        for (int i = tid; i < 64 * (K / 8); i += 256) {
            int r = i >> 4, c8 = i & 15;
            int gr = rowb + r;
            h8 v;
            if (gr < N) v = *(const h8*)((const _Float16*)x + (size_t)gr * K + c8 * 8);
            else        v = (h8)(_Float16)0.f;
            *(h8*)(As + r * LDK + c8 * 8) = v;
        }
    }
    for (int i = tid; i < F * (K / 8); i += 256) {
        int n = i >> 4, k8 = i & 15;
        *(h8*)(Wt + n * LDK + k8 * 8) = *(const h8*)(Wg + n * 128 + k8 * 8);
    }
    __syncthreads();

    f4 acc[NT];
#pragma unroll
    for (int nt = 0; nt < NT; nt++) acc[nt] = (f4)0.f;

    const _Float16* aw = As + (wave * 16 + c) * LDK + q * 8;
#pragma unroll
    for (int kt = 0; kt < 4; kt++) {
        h8 af = *(const h8*)(aw + kt * 32);
#pragma unroll
        for (int nt = 0; nt < NT; nt++) {
            h8 bf = *(const h8*)(Wt + (nt * 16 + c) * LDK + kt * 32 + q * 8);
            acc[nt] = __builtin_amdgcn_mfma_f32_16x16x32_f16(af, bf, acc[nt], 0, 0, 0);
        }
    }

    float asl[NT], adl[NT];
#pragma unroll
    for (int nt = 0; nt < NT; nt++) {
        asl[nt] = a_s[nt * 16 + c];
        adl[nt] = a_d[nt * 16 + c];
    }
    const int row0 = rowb + wave * 16 + q * 4;
#pragma unroll
    for (int r = 0; r < 4; r++) {
        int row = row0 + r;
        if (row < N) {
            float ps = 0.f, pd = 0.f;
#pragma unroll
            for (int nt = 0; nt < NT; nt++) {
                float v = acc[nt][r];
                hh[(size_t)row * F + nt * 16 + c] = (_Float16)v;
                ps += v * asl[nt];
                pd += v * adl[nt];
            }
#pragma unroll
            for (int off = 8; off >= 1; off >>= 1) {
                ps += __shfl_down(ps, off, 16);
                pd += __shfl_down(pd, off, 16);
            }
            if (c == 0) { alphaS[row] = ps; alphaD[row] = pd; }
        }
    }
}

// ---------------------------------------------------------------------------
// Layer-1 aggregation with PRECOMPUTED edge weights + denominators.
// Per edge: one int2 broadcast load {src, w} + one 16 B row gather + 8 fma.
// No aS gathers, no exp, no denominator reduce. F=128, LPE=16, EPW=4, NS=4.
// ---------------------------------------------------------------------------
__global__ __launch_bounds__(256) void gat_aggregate_pre(
    const int* __restrict__ row_start, const int* __restrict__ row_end,
    const int2* __restrict__ sw, const __half* __restrict__ hh,
    const float* __restrict__ denom1,
    const float* __restrict__ aS, const float* __restrict__ aD,
    const float* __restrict__ bias, __half* __restrict__ out, int N)
{
    const int i = blockIdx.x * 4 + (threadIdx.x >> 6);
    if (i >= N) return;
    const int lane = threadIdx.x & 63;
    const int sub = lane >> 4;
    const int l = lane & 15;

    const int start = row_start[i];
    const int end = row_end[i];

    float accA[8], accB[8];
#pragma unroll
    for (int q = 0; q < 8; q++) { accA[q] = 0.f; accB[q] = 0.f; }

    const int2 none = make_int2(-1, 0);
    int e = start + sub;
    int2 p0 = (e + 0 * 4 < end) ? sw[e + 0 * 4] : none;
    int2 p1 = (e + 1 * 4 < end) ? sw[e + 1 * 4] : none;
    int2 p2 = (e + 2 * 4 < end) ? sw[e + 2 * 4] : none;
    int2 p3 = (e + 3 * 4 < end) ? sw[e + 3 * 4] : none;

    while (p0.x >= 0) {
        int eb = e + 16;
        int2 n0 = (eb + 0 * 4 < end) ? sw[eb + 0 * 4] : none;
        int2 n1 = (eb + 1 * 4 < end) ? sw[eb + 1 * 4] : none;
        int2 n2 = (eb + 2 * 4 < end) ? sw[eb + 2 * 4] : none;
        int2 n3 = (eb + 3 * 4 < end) ? sw[eb + 3 * 4] : none;

#define PRE_BODY(P, ACC)                                                     \
        if (P.x >= 0) {                                                      \
            float w = __int_as_float(P.y);                                   \
            uint4 uu = *(const uint4*)(hh + (size_t)P.x * 128 + l * 8);      \
            const __half2* hp = (const __half2*)&uu;                         \
            _Pragma("unroll")                                                \
            for (int q = 0; q < 4; q++) {                                    \
                float2 f = __half22float2(hp[q]);                            \
                ACC[q * 2] += w * f.x; ACC[q * 2 + 1] += w * f.y;             \
            }                                                                \
        }

        PRE_BODY(p0, accA)
        PRE_BODY(p1, accB)
        PRE_BODY(p2, accA)
        PRE_BODY(p3, accB)
#undef PRE_BODY

        e = eb;
        p0 = n0; p1 = n1; p2 = n2; p3 = n3;
    }

    float acc[8];
#pragma unroll
    for (int q = 0; q < 8; q++) acc[q] = accA[q] + accB[q];

#pragma unroll
    for (int off = 32; off >= 16; off >>= 1) {
#pragma unroll
        for (int q = 0; q < 8; q++) acc[q] += __shfl_down(acc[q], off);
    }

    if (sub == 0) {
        float wsf = __expf(leaky(aS[i] + aD[i]));
        uint4 u = *(const uint4*)(hh + (size_t)i * 128 + l * 8);
        const __half2* hp = (const __half2*)&u;
        float inv = 1.f / (denom1[i] + wsf);
        float4 b0 = *(const float4*)(bias + l * 8);
        float4 b1v = *(const float4*)(bias + l * 8 + 4);
        float o[8];
#pragma unroll
        for (int q = 0; q < 4; q++) {
            float2 f = __half22float2(hp[q]);
            o[q * 2]     = (acc[q * 2]     + wsf * f.x) * inv;
            o[q * 2 + 1] = (acc[q * 2 + 1] + wsf * f.y) * inv;
        }
        o[0] += b0.x; o[1] += b0.y; o[2] += b0.z; o[3] += b0.w;
        o[4] += b1v.x; o[5] += b1v.y; o[6] += b1v.z; o[7] += b1v.w;
        h8 hv;
#pragma unroll
        for (int q = 0; q < 8; q++) hv[q] = (_Float16)fmaxf(o[q], 0.f);
        *(h8*)(out + (size_t)i * 128 + l * 8) = hv;
    }
}

// ---------------------------------------------------------------------------
// Layer-2 aggregation (round-1 semantics): inline aS gather + exp; src index
// read from sw[].x. F=64, LPE=8, EPW=8, NS=4. fp32 output to d_out.
// ---------------------------------------------------------------------------
#define EDGE_BODY(SV, ACC, DEN)                                              \
    if (SV >= 0) {                                                           \
        float w = __expf(leaky(aS[SV] + adi));                               \
        uint4 uu = *(const uint4*)(hh + (size_t)SV * 64 + l * 8);            \
        const __half2* hp = (const __half2*)&uu;                             \
        _Pragma("unroll")                                                    \
        for (int q = 0; q < 4; q++) {                                        \
            float2 f = __half22float2(hp[q]);                                \
            ACC[q * 2] += w * f.x; ACC[q * 2 + 1] += w * f.y;                 \
        }                                                                    \
        DEN += w;                                                            \
    }

__global__ __launch_bounds__(256) void gat_aggregate2(
    const int* __restrict__ row_start, const int* __restrict__ row_end,
    const int2* __restrict__ sw, const __half* __restrict__ hh,
    const float* __restrict__ aS, const float* __restrict__ aD,
    const float* __restrict__ bias, float* __restrict__ out, int N)
{
    constexpr int EPW = 8;              // 64 lanes / LPE(8)

    const int i = blockIdx.x * 4 + (threadIdx.x >> 6);
    if (i >= N) return;
    const int lane = threadIdx.x & 63;
    const int sub = lane >> 3;
    const int l = lane & 7;

    const float adi = aD[i];
    const int start = row_start[i];
    const int end = row_end[i];

    float accA[8], accB[8];
#pragma unroll
    for (int q = 0; q < 8; q++) { accA[q] = 0.f; accB[q] = 0.f; }
    float denA = 0.f, denB = 0.f;

    int e = start + sub;
    int s0 = (e + 0 * EPW < end) ? sw[e + 0 * EPW].x : -1;
    int s1 = (e + 1 * EPW < end) ? sw[e + 1 * EPW].x : -1;
    int s2 = (e + 2 * EPW < end) ? sw[e + 2 * EPW].x : -1;
    int s3 = (e + 3 * EPW < end) ? sw[e + 3 * EPW].x : -1;

    while (s0 >= 0) {
        int eb = e + 4 * EPW;
        int n0 = (eb + 0 * EPW < end) ? sw[eb + 0 * EPW].x : -1;
        int n1 = (eb + 1 * EPW < end) ? sw[eb + 1 * EPW].x : -1;
        int n2 = (eb + 2 * EPW < end) ? sw[eb + 2 * EPW].x : -1;
        int n3 = (eb + 3 * EPW < end) ? sw[eb + 3 * EPW].x : -1;

        EDGE_BODY(s0, accA, denA)
        EDGE_BODY(s1, accB, denB)
        EDGE_BODY(s2, accA, denA)
        EDGE_BODY(s3, accB, denB)

        e = eb;
        s0 = n0; s1 = n1; s2 = n2; s3 = n3;
    }

    float acc[8];
#pragma unroll
    for (int q = 0; q < 8; q++) acc[q] = accA[q] + accB[q];
    float denom = denA + denB;

#pragma unroll
    for (int off = 32; off >= 8; off >>= 1) {
#pragma unroll
        for (int q = 0; q < 8; q++) acc[q] += __shfl_down(acc[q], off);
        denom += __shfl_down(denom, off);
    }

    if (sub == 0) {
        float wsf = __expf(leaky(aS[i] + adi));
        uint4 u = *(const uint4*)(hh + (size_t)i * 64 + l * 8);
        const __half2* hp = (const __half2*)&u;
        float inv = 1.f / (denom + wsf);
        float4 b0 = *(const float4*)(bias + l * 8);
        float4 b1 = *(const float4*)(bias + l * 8 + 4);
        float o[8];
#pragma unroll
        for (int q = 0; q < 4; q++) {
            float2 f = __half22float2(hp[q]);
            o[q * 2]     = (acc[q * 2]     + wsf * f.x) * inv;
            o[q * 2 + 1] = (acc[q * 2 + 1] + wsf * f.y) * inv;
        }
        o[0] += b0.x; o[1] += b0.y; o[2] += b0.z; o[3] += b0.w;
        o[4] += b1.x; o[5] += b1.y; o[6] += b1.z; o[7] += b1.w;
        *(float4*)(out + (size_t)i * 64 + l * 8)     = make_float4(o[0], o[1], o[2], o[3]);
        *(float4*)(out + (size_t)i * 64 + l * 8 + 4) = make_float4(o[4], o[5], o[6], o[7]);
    }
}

extern "C" void kernel_launch(void* const* d_in, const int* in_sizes, int n_in,
                              void* d_out, int out_size, void* d_ws, size_t ws_size,
                              hipStream_t stream)
{
    const float* x   = (const float*)d_in[0];
    const int*   ei  = (const int*)d_in[1];
    const float* W1  = (const float*)d_in[2];
    const float* aS1 = (const float*)d_in[3];
    const float* aD1 = (const float*)d_in[4];
    const float* b1  = (const float*)d_in[5];
    const float* W2  = (const float*)d_in[6];
    const float* aS2 = (const float*)d_in[7];
    const float* aD2 = (const float*)d_in[8];
    const float* b2  = (const float*)d_in[9];

    const int K = 128, F1 = 128, F2 = 64;
    const int N = in_sizes[0] / K;   // 50000 (< 65536: packed u32 staging valid)
    const int E = in_sizes[1] / 2;
    const int* src = ei;
    const int* dst = ei + E;

    const int Np = (N + 4) & ~3;
    const int NB = (N + 255) >> 8;
    const int nbt = (E + TILE - 1) / TILE;
    const int nblk_gemm = (N + 63) / 64;
    int cap = (((E / NB) * 3) / 2 + 255) & ~255;   // 1.5x mean, 256-aligned
    if (cap > CSR_CAP) cap = CSR_CAP;

    char* wsb = (char*)d_ws;
    int* bfill        = (int*)wsb;      wsb += 256 * 4;                       // zeroed by prep
    _Float16* W1t     = (_Float16*)wsb; wsb += 128 * 128 * 2;                 // fp16 W1^T [n][k]
    _Float16* W2t     = (_Float16*)wsb; wsb += 64 * 128 * 2;                  // fp16 W2^T [n][k]
    int* row_start    = (int*)wsb;      wsb += (size_t)Np * 4;
    int* row_end      = (int*)wsb;      wsb += (size_t)Np * 4;
    unsigned* staging = (unsigned*)wsb; wsb += (size_t)NB * CSR_CAP * 4;
    int2* sw_sorted   = (int2*)wsb;     wsb += (size_t)NB * CSR_CAP * 8;      // {src, w} per edge
    float* denom1     = (float*)wsb;    wsb += (size_t)Np * 4;
    _Float16* hh1     = (_Float16*)wsb; wsb += (size_t)N * F1 * 2;
    _Float16* x2h     = (_Float16*)wsb; wsb += (size_t)N * F1 * 2;
    _Float16* hh2     = (_Float16*)wsb; wsb += (size_t)N * F2 * 2;
    float* as_        = (float*)wsb;    wsb += (size_t)Np * 4;
    float* ad_        = (float*)wsb;    wsb += (size_t)Np * 4;
    float* as2_       = (float*)wsb;    wsb += (size_t)Np * 4;
    float* ad2_       = (float*)wsb;    wsb += (size_t)Np * 4;

    dim3 blk(256);

    // ---- prep: zero bfill + fp16 W transposes ----
    prep<<<dim3(12), blk, 0, stream>>>(W1, W2, W1t, W2t, bfill);

    // ---- layer-1 GEMM (MFMA) overlapped with bucket_scatter ----
    gemm1_scatter<<<dim3(nblk_gemm + nbt), blk, 0, stream>>>(
        x, W1t, aS1, aD1, hh1, as_, ad_, N, nblk_gemm,
        src, dst, bfill, staging, cap, E);

    // ---- CSR finalize + layer-1 edge weights/denoms ----
    bucket_to_csr<<<dim3(NB), dim3(512), 0, stream>>>(
        staging, bfill, row_start, row_end, sw_sorted, denom1, as_, ad_, cap, N);

    // ---- layer-1 aggregate (precomputed weights) -> fp16 x2 ----
    gat_aggregate_pre<<<dim3((N + 3) / 4), blk, 0, stream>>>(
        row_start, row_end, sw_sorted, (const __half*)hh1, denom1, as_, ad_, b1,
        (__half*)x2h, N);

    // ---- layer-2 GEMM (MFMA, fp16 input) ----
    gemm_mfma<F2, _Float16><<<dim3((N + 63) / 64), blk, 0, stream>>>(
        x2h, W2t, aS2, aD2, hh2, as2_, ad2_, N);

    // ---- layer-2 aggregate -> d_out ----
    gat_aggregate2<<<dim3((N + 3) / 4), blk, 0, stream>>>(
        row_start, row_end, sw_sorted, (const __half*)hh2, as2_, ad2_, b2,
        (float*)d_out, N);
}

// Round 7
// 189.241 us; speedup vs baseline: 1.0807x; 1.0807x over previous
//
#include <hip/hip_runtime.h>
#include <hip/hip_fp16.h>
#include <cstddef>

#define NEG_SLOPE 0.2f
#define TILE 4096
#define CSR_CAP 6144   // fixed per-bucket capacity; mean ~4096, sigma ~64

typedef _Float16 h8 __attribute__((ext_vector_type(8)));
typedef _Float16 h4 __attribute__((ext_vector_type(4)));
typedef float f4 __attribute__((ext_vector_type(4)));

__device__ __forceinline__ float leaky(float x) { return x >= 0.f ? x : NEG_SLOPE * x; }

__device__ __forceinline__ int wave_iscan(int v, int lane) {
#pragma unroll
    for (int off = 1; off < 64; off <<= 1) {
        int t = __shfl_up(v, off);
        if (lane >= off) v += t;
    }
    return v;
}

// ---------------------------------------------------------------------------
// prep: zero bfill + one-time fp16 transpose of W1 (128x128) and W2 (128x64).
// ---------------------------------------------------------------------------
__global__ __launch_bounds__(256) void prep(
    const float* __restrict__ W1, const float* __restrict__ W2,
    _Float16* __restrict__ W1t, _Float16* __restrict__ W2t,
    int* __restrict__ bfill)
{
    const int b = blockIdx.x;
    const int tid = threadIdx.x;
    if (b == 0) bfill[tid] = 0;
    if (b < 8) {
        for (int i = b * 2048 + tid; i < (b + 1) * 2048; i += 256) {
            int n = i >> 7, k = i & 127;
            W1t[n * 128 + k] = (_Float16)W1[k * 128 + n];
        }
    } else {
        const int bb = b - 8;
        for (int i = bb * 2048 + tid; i < (bb + 1) * 2048; i += 256) {
            int n = i >> 7, k = i & 127;  // n in [0,64)
            W2t[n * 128 + k] = (_Float16)W2[k * 64 + n];
        }
    }
}

// ---------------------------------------------------------------------------
// Shared GEMM tile body (layer-1, F=128): rows [rowb, rowb+64).
// ---------------------------------------------------------------------------
struct GemmLds { _Float16 As[64 * 136]; _Float16 Wt[128 * 136]; };

__device__ __forceinline__ void gemm1_tile(
    GemmLds& g, int tid, int rowb,
    const float* __restrict__ x, const _Float16* __restrict__ Wg,
    const float* __restrict__ a_s, const float* __restrict__ a_d,
    _Float16* __restrict__ hh, float* __restrict__ alphaS, float* __restrict__ alphaD,
    int N)
{
    constexpr int K = 128;
    constexpr int LDK = K + 8;
    constexpr int F = 128;
    constexpr int NT = F / 16;

    const int wave = tid >> 6;
    const int lane = tid & 63;
    const int q = lane >> 4;
    const int c = lane & 15;

    for (int i = tid; i < 64 * (K / 4); i += 256) {
        int r = i >> 5, c4 = i & 31;
        int gr = rowb + r;
        float4 v = (gr < N) ? *(const float4*)(x + (size_t)gr * K + c4 * 4)
                            : make_float4(0.f, 0.f, 0.f, 0.f);
        h4 hv = { (_Float16)v.x, (_Float16)v.y, (_Float16)v.z, (_Float16)v.w };
        *(h4*)(g.As + r * LDK + c4 * 4) = hv;
    }
    for (int i = tid; i < F * (K / 8); i += 256) {
        int n = i >> 4, k8 = i & 15;
        *(h8*)(g.Wt + n * LDK + k8 * 8) = *(const h8*)(Wg + n * 128 + k8 * 8);
    }
    __syncthreads();

    f4 acc[NT];
#pragma unroll
    for (int nt = 0; nt < NT; nt++) acc[nt] = (f4)0.f;

    const _Float16* aw = g.As + (wave * 16 + c) * LDK + q * 8;
#pragma unroll
    for (int kt = 0; kt < 4; kt++) {
        h8 af = *(const h8*)(aw + kt * 32);
#pragma unroll
        for (int nt = 0; nt < NT; nt++) {
            h8 bf = *(const h8*)(g.Wt + (nt * 16 + c) * LDK + kt * 32 + q * 8);
            acc[nt] = __builtin_amdgcn_mfma_f32_16x16x32_f16(af, bf, acc[nt], 0, 0, 0);
        }
    }

    float asl[NT], adl[NT];
#pragma unroll
    for (int nt = 0; nt < NT; nt++) {
        asl[nt] = a_s[nt * 16 + c];
        adl[nt] = a_d[nt * 16 + c];
    }
    const int row0 = rowb + wave * 16 + q * 4;
#pragma unroll
    for (int r = 0; r < 4; r++) {
        int row = row0 + r;
        if (row < N) {
            float ps = 0.f, pd = 0.f;
#pragma unroll
            for (int nt = 0; nt < NT; nt++) {
                float v = acc[nt][r];
                hh[(size_t)row * F + nt * 16 + c] = (_Float16)v;
                ps += v * asl[nt];
                pd += v * adl[nt];
            }
#pragma unroll
            for (int off = 8; off >= 1; off >>= 1) {
                ps += __shfl_down(ps, off, 16);
                pd += __shfl_down(pd, off, 16);
            }
            if (c == 0) { alphaS[row] = ps; alphaD[row] = pd; }
        }
    }
}

// ---------------------------------------------------------------------------
// FAT A: blocks [0, gsplit) do gemm1 rows [0, gsplit*64); blocks
// [gsplit, gsplit+nbt) do bucket_scatter (LDS-sorted, coalesced staging).
// ---------------------------------------------------------------------------
__global__ __launch_bounds__(256) void fatA(
    const float* __restrict__ x, const _Float16* __restrict__ Wg,
    const float* __restrict__ a_s, const float* __restrict__ a_d,
    _Float16* __restrict__ hh, float* __restrict__ alphaS, float* __restrict__ alphaD,
    int N, int gsplit,
    const int* __restrict__ src, const int* __restrict__ dst,
    int* __restrict__ bfill, unsigned* __restrict__ staging, int cap, int E)
{
    __shared__ union {
        GemmLds g;
        struct {
            int lcnt[256]; int loff[256]; int gbase[256]; int ws[4];
            unsigned pairs[TILE]; unsigned char bkt[TILE];
        } s;
    } u;

    const int tid = threadIdx.x;

    if (blockIdx.x < (unsigned)gsplit) {
        gemm1_tile(u.g, tid, blockIdx.x * 64, x, Wg, a_s, a_d, hh, alphaS, alphaD, N);
    } else {
        // ================= bucket_scatter path =================
        const int base = (blockIdx.x - gsplit) * TILE;
        const int vt = min(TILE, E - base);

        u.s.lcnt[tid] = 0;
        __syncthreads();

        int d[TILE / 256], s[TILE / 256], r[TILE / 256];
#pragma unroll
        for (int j = 0; j < TILE / 256; j++) {
            int idx = base + j * 256 + tid;
            if (idx < E) {
                d[j] = dst[idx]; s[j] = src[idx];
                r[j] = atomicAdd(&u.s.lcnt[d[j] >> 8], 1);
            } else d[j] = -1;
        }
        __syncthreads();
        {
            int lane = tid & 63, wid = tid >> 6;
            int v = u.s.lcnt[tid];
            int incl = wave_iscan(v, lane);
            if (lane == 63) u.s.ws[wid] = incl;
            __syncthreads();
            int woff = 0;
            for (int w = 0; w < wid; w++) woff += u.s.ws[w];
            u.s.loff[tid] = woff + incl - v;
        }
        __syncthreads();
        {
            int c = u.s.lcnt[tid];
            if (c > 0) u.s.gbase[tid] = tid * cap + atomicAdd(&bfill[tid], c);
        }
        __syncthreads();
#pragma unroll
        for (int j = 0; j < TILE / 256; j++) {
            if (d[j] >= 0) {
                int b = d[j] >> 8;
                int slot = u.s.loff[b] + r[j];
                u.s.pairs[slot] = ((unsigned)d[j] << 16) | (unsigned)s[j];
                u.s.bkt[slot] = (unsigned char)b;
            }
        }
        __syncthreads();
        for (int slot = tid; slot < vt; slot += 256) {
            int b = u.s.bkt[slot];
            staging[u.s.gbase[b] + (slot - u.s.loff[b])] = u.s.pairs[slot];
        }
    }
}

// ---------------------------------------------------------------------------
// FAT B: blocks [0, ncsr) do bucket_to_csr (256-thread variant, hidden under
// the remaining GEMM blocks); blocks [ncsr, ...) do gemm1 rows
// [gsplit*64, ...). csr depends only on fatA (stream-ordered) -- no
// intra-dispatch ordering assumptions.
// ---------------------------------------------------------------------------
__global__ __launch_bounds__(256) void fatB(
    const float* __restrict__ x, const _Float16* __restrict__ Wg,
    const float* __restrict__ a_s, const float* __restrict__ a_d,
    _Float16* __restrict__ hh, float* __restrict__ alphaS, float* __restrict__ alphaD,
    int N, int gsplit, int ncsr,
    const unsigned* __restrict__ staging, const int* __restrict__ bfill,
    int* __restrict__ row_start, int* __restrict__ row_end,
    int* __restrict__ src_sorted, int cap)
{
    __shared__ union {
        GemmLds g;
        struct {
            unsigned lp[CSR_CAP];
            int lcnt[256]; int loff[256]; int lfill[256]; int ws[4];
        } c;
    } u;

    const int tid = threadIdx.x;

    if (blockIdx.x >= (unsigned)ncsr) {
        gemm1_tile(u.g, tid, (gsplit + blockIdx.x - ncsr) * 64,
                   x, Wg, a_s, a_d, hh, alphaS, alphaD, N);
    } else {
        // ================= bucket_to_csr path (256 threads) =================
        const int b = blockIdx.x;
        const int beg = b * cap;
        const int len = bfill[b];

        u.c.lcnt[tid] = 0;
        __syncthreads();
        for (int p = tid; p < len; p += 256) {
            unsigned v = staging[beg + p];
            u.c.lp[p] = v;  // len <= cap <= CSR_CAP
            atomicAdd(&u.c.lcnt[(v >> 16) & 255], 1);
        }
        __syncthreads();
        {
            int lane = tid & 63, wid = tid >> 6;
            int v = u.c.lcnt[tid];
            int incl = wave_iscan(v, lane);
            if (lane == 63) u.c.ws[wid] = incl;
            __syncthreads();
            int woff = 0;
            for (int w = 0; w < wid; w++) woff += u.c.ws[w];
            int excl = woff + incl - v;
            u.c.loff[tid] = excl;
            u.c.lfill[tid] = excl;
            int node = (b << 8) + tid;
            if (node < N) { row_start[node] = beg + excl; row_end[node] = beg + excl + v; }
        }
        __syncthreads();
        for (int p = tid; p < len; p += 256) {
            unsigned v = u.c.lp[p];
            int pos = atomicAdd(&u.c.lfill[(v >> 16) & 255], 1);
            src_sorted[beg + pos] = (int)(v & 0xFFFFu);
        }
    }
}

// ---------------------------------------------------------------------------
// MFMA GEMM + fused alpha dots (layer 2, fp16 input, pre-transposed fp16 W).
// ---------------------------------------------------------------------------
template <int F, typename IT>
__global__ __launch_bounds__(256) void gemm_mfma(
    const IT* __restrict__ x, const _Float16* __restrict__ Wg,
    const float* __restrict__ a_s, const float* __restrict__ a_d,
    _Float16* __restrict__ hh, float* __restrict__ alphaS, float* __restrict__ alphaD,
    int N)
{
    constexpr int K = 128;
    constexpr int LDK = K + 8;
    constexpr int NT = F / 16;

    __shared__ _Float16 As[64 * LDK];
    __shared__ _Float16 Wt[F * LDK];

    const int tid = threadIdx.x;
    const int wave = tid >> 6;
    const int lane = tid & 63;
    const int q = lane >> 4;
    const int c = lane & 15;
    const int rowb = blockIdx.x * 64;

    if constexpr (sizeof(IT) == 4) {
        for (int i = tid; i < 64 * (K / 4); i += 256) {
            int r = i >> 5, c4 = i & 31;
            int gr = rowb + r;
            float4 v = (gr < N) ? *(const float4*)((const float*)x + (size_t)gr * K + c4 * 4)
                                : make_float4(0.f, 0.f, 0.f, 0.f);
            h4 hv = { (_Float16)v.x, (_Float16)v.y, (_Float16)v.z, (_Float16)v.w };
            *(h4*)(As + r * LDK + c4 * 4) = hv;
        }
    } else {
        for (int i = tid; i < 64 * (K / 8); i += 256) {
            int r = i >> 4, c8 = i & 15;
            int gr = rowb + r;
            h8 v;
            if (gr < N) v = *(const h8*)((const _Float16*)x + (size_t)gr * K + c8 * 8);
            else        v = (h8)(_Float16)0.f;
            *(h8*)(As + r * LDK + c8 * 8) = v;
        }
    }
    for (int i = tid; i < F * (K / 8); i += 256) {
        int n = i >> 4, k8 = i & 15;
        *(h8*)(Wt + n * LDK + k8 * 8) = *(const h8*)(Wg + n * 128 + k8 * 8);
    }
    __syncthreads();

    f4 acc[NT];
#pragma unroll
    for (int nt = 0; nt < NT; nt++) acc[nt] = (f4)0.f;

    const _Float16* aw = As + (wave * 16 + c) * LDK + q * 8;
#pragma unroll
    for (int kt = 0; kt < 4; kt++) {
        h8 af = *(const h8*)(aw + kt * 32);
#pragma unroll
        for (int nt = 0; nt < NT; nt++) {
            h8 bf = *(const h8*)(Wt + (nt * 16 + c) * LDK + kt * 32 + q * 8);
            acc[nt] = __builtin_amdgcn_mfma_f32_16x16x32_f16(af, bf, acc[nt], 0, 0, 0);
        }
    }

    float asl[NT], adl[NT];
#pragma unroll
    for (int nt = 0; nt < NT; nt++) {
        asl[nt] = a_s[nt * 16 + c];
        adl[nt] = a_d[nt * 16 + c];
    }
    const int row0 = rowb + wave * 16 + q * 4;
#pragma unroll
    for (int r = 0; r < 4; r++) {
        int row = row0 + r;
        if (row < N) {
            float ps = 0.f, pd = 0.f;
#pragma unroll
            for (int nt = 0; nt < NT; nt++) {
                float v = acc[nt][r];
                hh[(size_t)row * F + nt * 16 + c] = (_Float16)v;
                ps += v * asl[nt];
                pd += v * adl[nt];
            }
#pragma unroll
            for (int off = 8; off >= 1; off >>= 1) {
                ps += __shfl_down(ps, off, 16);
                pd += __shfl_down(pd, off, 16);
            }
            if (c == 0) { alphaS[row] = ps; alphaD[row] = pd; }
        }
    }
}

// ---------------------------------------------------------------------------
// Fused per-destination aggregation (round-1 verified): fp16 gather 16 B/lane,
// 4-stream edge unroll with index prefetch. Output fp16 or fp32.
// ---------------------------------------------------------------------------
template <int F, bool RELU, typename OT>
__global__ __launch_bounds__(256) void gat_aggregate(
    const int* __restrict__ row_start, const int* __restrict__ row_end,
    const int* __restrict__ src_sorted, const __half* __restrict__ hh,
    const float* __restrict__ aS, const float* __restrict__ aD,
    const float* __restrict__ bias, OT* __restrict__ out, int N)
{
    constexpr int LPE = F / 8;          // lanes per edge (16 or 8)
    constexpr int EPW = 64 / LPE;       // edge slots per wave (4 or 8)

    const int i = blockIdx.x * 4 + (threadIdx.x >> 6);
    if (i >= N) return;
    const int lane = threadIdx.x & 63;
    const int sub = lane / LPE;
    const int l = lane % LPE;

    const float adi = aD[i];
    const int start = row_start[i];
    const int end = row_end[i];

    float accA[8], accB[8];
#pragma unroll
    for (int q = 0; q < 8; q++) { accA[q] = 0.f; accB[q] = 0.f; }
    float denA = 0.f, denB = 0.f;

    int e = start + sub;
    int s0 = (e + 0 * EPW < end) ? src_sorted[e + 0 * EPW] : -1;
    int s1 = (e + 1 * EPW < end) ? src_sorted[e + 1 * EPW] : -1;
    int s2 = (e + 2 * EPW < end) ? src_sorted[e + 2 * EPW] : -1;
    int s3 = (e + 3 * EPW < end) ? src_sorted[e + 3 * EPW] : -1;

    while (s0 >= 0) {
        int eb = e + 4 * EPW;
        int n0 = (eb + 0 * EPW < end) ? src_sorted[eb + 0 * EPW] : -1;
        int n1 = (eb + 1 * EPW < end) ? src_sorted[eb + 1 * EPW] : -1;
        int n2 = (eb + 2 * EPW < end) ? src_sorted[eb + 2 * EPW] : -1;
        int n3 = (eb + 3 * EPW < end) ? src_sorted[eb + 3 * EPW] : -1;

        {
            float w = __expf(leaky(aS[s0] + adi));
            uint4 u = *(const uint4*)(hh + (size_t)s0 * F + l * 8);
            const __half2* hp = (const __half2*)&u;
#pragma unroll
            for (int q = 0; q < 4; q++) {
                float2 f = __half22float2(hp[q]);
                accA[q * 2] += w * f.x; accA[q * 2 + 1] += w * f.y;
            }
            denA += w;
        }
        if (s1 >= 0) {
            float w = __expf(leaky(aS[s1] + adi));
            uint4 u = *(const uint4*)(hh + (size_t)s1 * F + l * 8);
            const __half2* hp = (const __half2*)&u;
#pragma unroll
            for (int q = 0; q < 4; q++) {
                float2 f = __half22float2(hp[q]);
                accB[q * 2] += w * f.x; accB[q * 2 + 1] += w * f.y;
            }
            denB += w;
        }
        if (s2 >= 0) {
            float w = __expf(leaky(aS[s2] + adi));
            uint4 u = *(const uint4*)(hh + (size_t)s2 * F + l * 8);
            const __half2* hp = (const __half2*)&u;
#pragma unroll
            for (int q = 0; q < 4; q++) {
                float2 f = __half22float2(hp[q]);
                accA[q * 2] += w * f.x; accA[q * 2 + 1] += w * f.y;
            }
            denA += w;
        }
        if (s3 >= 0) {
            float w = __expf(leaky(aS[s3] + adi));
            uint4 u = *(const uint4*)(hh + (size_t)s3 * F + l * 8);
            const __half2* hp = (const __half2*)&u;
#pragma unroll
            for (int q = 0; q < 4; q++) {
                float2 f = __half22float2(hp[q]);
                accB[q * 2] += w * f.x; accB[q * 2 + 1] += w * f.y;
            }
            denB += w;
        }
        e = eb;
        s0 = n0; s1 = n1; s2 = n2; s3 = n3;
    }

    float acc[8];
#pragma unroll
    for (int q = 0; q < 8; q++) acc[q] = accA[q] + accB[q];
    float denom = denA + denB;

#pragma unroll
    for (int off = 32; off >= LPE; off >>= 1) {
#pragma unroll
        for (int q = 0; q < 8; q++) acc[q] += __shfl_down(acc[q], off);
        denom += __shfl_down(denom, off);
    }

    if (sub == 0) {
        float wsf = __expf(leaky(aS[i] + adi));
        uint4 u = *(const uint4*)(hh + (size_t)i * F + l * 8);
        const __half2* hp = (const __half2*)&u;
        float inv = 1.f / (denom + wsf);
        float4 b0 = *(const float4*)(bias + l * 8);
        float4 b1 = *(const float4*)(bias + l * 8 + 4);
        float o[8];
#pragma unroll
        for (int q = 0; q < 4; q++) {
            float2 f = __half22float2(hp[q]);
            o[q * 2]     = (acc[q * 2]     + wsf * f.x) * inv;
            o[q * 2 + 1] = (acc[q * 2 + 1] + wsf * f.y) * inv;
        }
        o[0] += b0.x; o[1] += b0.y; o[2] += b0.z; o[3] += b0.w;
        o[4] += b1.x; o[5] += b1.y; o[6] += b1.z; o[7] += b1.w;
        if (RELU) {
#pragma unroll
            for (int q = 0; q < 8; q++) o[q] = fmaxf(o[q], 0.f);
        }
        if constexpr (sizeof(OT) == 2) {
            __half2 qh[4];
            qh[0] = __floats2half2_rn(o[0], o[1]);
            qh[1] = __floats2half2_rn(o[2], o[3]);
            qh[2] = __floats2half2_rn(o[4], o[5]);
            qh[3] = __floats2half2_rn(o[6], o[7]);
            *(uint4*)((__half*)out + (size_t)i * F + l * 8) = *(uint4*)qh;
        } else {
            *(float4*)((float*)out + (size_t)i * F + l * 8)     = make_float4(o[0], o[1], o[2], o[3]);
            *(float4*)((float*)out + (size_t)i * F + l * 8 + 4) = make_float4(o[4], o[5], o[6], o[7]);
        }
    }
}

extern "C" void kernel_launch(void* const* d_in, const int* in_sizes, int n_in,
                              void* d_out, int out_size, void* d_ws, size_t ws_size,
                              hipStream_t stream)
{
    const float* x   = (const float*)d_in[0];
    const int*   ei  = (const int*)d_in[1];
    const float* W1  = (const float*)d_in[2];
    const float* aS1 = (const float*)d_in[3];
    const float* aD1 = (const float*)d_in[4];
    const float* b1  = (const float*)d_in[5];
    const float* W2  = (const float*)d_in[6];
    const float* aS2 = (const float*)d_in[7];
    const float* aD2 = (const float*)d_in[8];
    const float* b2  = (const float*)d_in[9];

    const int K = 128, F1 = 128, F2 = 64;
    const int N = in_sizes[0] / K;   // 50000 (< 65536: packed u32 staging valid)
    const int E = in_sizes[1] / 2;
    const int* src = ei;
    const int* dst = ei + E;

    const int Np = (N + 4) & ~3;
    const int NB = (N + 255) >> 8;
    const int nbt = (E + TILE - 1) / TILE;
    const int nblk_gemm = (N + 63) / 64;
    const int gsplit = (nblk_gemm * 5) / 8;        // gemm blocks in fatA
    int cap = (((E / NB) * 3) / 2 + 255) & ~255;   // 1.5x mean, 256-aligned
    if (cap > CSR_CAP) cap = CSR_CAP;

    char* wsb = (char*)d_ws;
    int* bfill        = (int*)wsb;      wsb += 256 * 4;                       // zeroed by prep
    _Float16* W1t     = (_Float16*)wsb; wsb += 128 * 128 * 2;                 // fp16 W1^T [n][k]
    _Float16* W2t     = (_Float16*)wsb; wsb += 64 * 128 * 2;                  // fp16 W2^T [n][k]
    int* row_start    = (int*)wsb;      wsb += (size_t)Np * 4;
    int* row_end      = (int*)wsb;      wsb += (size_t)Np * 4;
    unsigned* staging = (unsigned*)wsb; wsb += (size_t)NB * CSR_CAP * 4;
    int* src_sorted   = (int*)wsb;      wsb += (size_t)NB * CSR_CAP * 4;
    _Float16* hh1     = (_Float16*)wsb; wsb += (size_t)N * F1 * 2;
    _Float16* x2h     = (_Float16*)wsb; wsb += (size_t)N * F1 * 2;
    _Float16* hh2     = (_Float16*)wsb; wsb += (size_t)N * F2 * 2;
    float* as_        = (float*)wsb;    wsb += (size_t)Np * 4;
    float* ad_        = (float*)wsb;    wsb += (size_t)Np * 4;
    float* as2_       = (float*)wsb;    wsb += (size_t)Np * 4;
    float* ad2_       = (float*)wsb;    wsb += (size_t)Np * 4;

    dim3 blk(256);

    // ---- prep: zero bfill + fp16 W transposes ----
    prep<<<dim3(12), blk, 0, stream>>>(W1, W2, W1t, W2t, bfill);

    // ---- fat A: gemm1 rows [0, gsplit*64) overlapped with bucket_scatter ----
    fatA<<<dim3(gsplit + nbt), blk, 0, stream>>>(
        x, W1t, aS1, aD1, hh1, as_, ad_, N, gsplit,
        src, dst, bfill, staging, cap, E);

    // ---- fat B: bucket_to_csr hidden under gemm1 rows [gsplit*64, N) ----
    fatB<<<dim3(NB + (nblk_gemm - gsplit)), blk, 0, stream>>>(
        x, W1t, aS1, aD1, hh1, as_, ad_, N, gsplit, NB,
        staging, bfill, row_start, row_end, src_sorted, cap);

    // ---- layer-1 aggregate -> fp16 x2 ----
    gat_aggregate<F1, true, __half><<<dim3((N + 3) / 4), blk, 0, stream>>>(
        row_start, row_end, src_sorted, (const __half*)hh1, as_, ad_, b1,
        (__half*)x2h, N);

    // ---- layer-2 GEMM (MFMA, fp16 input) ----
    gemm_mfma<F2, _Float16><<<dim3((N + 63) / 64), blk, 0, stream>>>(
        x2h, W2t, aS2, aD2, hh2, as2_, ad2_, N);

    // ---- layer-2 aggregate -> d_out ----
    gat_aggregate<F2, false, float><<<dim3((N + 3) / 4), blk, 0, stream>>>(
        row_start, row_end, src_sorted, (const __half*)hh2, as2_, ad2_, b2,
        (float*)d_out, N);
}

// Round 8
// 184.394 us; speedup vs baseline: 1.1091x; 1.0263x over previous
//
#include <hip/hip_runtime.h>
#include <hip/hip_fp16.h>
#include <cstddef>

#define NEG_SLOPE 0.2f
#define TILE 4096
#define CSR_CAP 6144   // fixed per-bucket capacity; mean ~4096, sigma ~64
#define LDKP 136       // padded K stride (bank-conflict-free ds_read_b128)

typedef _Float16 h8 __attribute__((ext_vector_type(8)));
typedef _Float16 h4 __attribute__((ext_vector_type(4)));
typedef float f4 __attribute__((ext_vector_type(4)));

__device__ __forceinline__ float leaky(float x) { return x >= 0.f ? x : NEG_SLOPE * x; }

__device__ __forceinline__ int wave_iscan(int v, int lane) {
#pragma unroll
    for (int off = 1; off < 64; off <<= 1) {
        int t = __shfl_up(v, off);
        if (lane >= off) v += t;
    }
    return v;
}

// Async global->LDS copy: nbytes must be a multiple of 1024 (64 lanes x 16 B).
// ldsbase wave-uniform; per-lane global source. Completed by __syncthreads().
__device__ __forceinline__ void gload_lds_chunks(
    const char* __restrict__ gsrc, char* ldsbase, int nbytes, int wave, int lane)
{
    const int nch = nbytes >> 10;
    for (int ch = wave; ch < nch; ch += 4) {
        __builtin_amdgcn_global_load_lds(
            (const __attribute__((address_space(1))) void*)(gsrc + ch * 1024 + lane * 16),
            (__attribute__((address_space(3))) void*)(ldsbase + ch * 1024),
            16, 0, 0);
    }
}

// ---------------------------------------------------------------------------
// prep: zero bfill + one-time fp16 transpose of W1/W2 into LDS-PADDED layout
// [n][LDKP] so GEMM blocks can stage Wt with linear global_load_lds chunks.
// Pad columns [128,136) are never read by the MFMA fragment loads.
// ---------------------------------------------------------------------------
__global__ __launch_bounds__(256) void prep(
    const float* __restrict__ W1, const float* __restrict__ W2,
    _Float16* __restrict__ W1t, _Float16* __restrict__ W2t,
    int* __restrict__ bfill)
{
    const int b = blockIdx.x;
    const int tid = threadIdx.x;
    if (b == 0) bfill[tid] = 0;
    if (b < 8) {
        for (int i = b * 2048 + tid; i < (b + 1) * 2048; i += 256) {
            int n = i >> 7, k = i & 127;
            W1t[n * LDKP + k] = (_Float16)W1[k * 128 + n];
        }
    } else {
        const int bb = b - 8;
        for (int i = bb * 2048 + tid; i < (bb + 1) * 2048; i += 256) {
            int n = i >> 7, k = i & 127;  // n in [0,64)
            W2t[n * LDKP + k] = (_Float16)W2[k * 64 + n];
        }
    }
}

// ---------------------------------------------------------------------------
// Shared GEMM tile body (layer-1, F=128): rows [rowb, rowb+64).
// Wt staged via async global_load_lds (34 KiB linear, padded source).
// ---------------------------------------------------------------------------
struct GemmLds { _Float16 As[64 * LDKP]; _Float16 Wt[128 * LDKP]; };

__device__ __forceinline__ void gemm1_tile(
    GemmLds& g, int tid, int rowb,
    const float* __restrict__ x, const _Float16* __restrict__ Wg,
    const float* __restrict__ a_s, const float* __restrict__ a_d,
    _Float16* __restrict__ hh, float* __restrict__ alphaS, float* __restrict__ alphaD,
    int N)
{
    constexpr int K = 128;
    constexpr int LDK = LDKP;
    constexpr int F = 128;
    constexpr int NT = F / 16;

    const int wave = tid >> 6;
    const int lane = tid & 63;
    const int q = lane >> 4;
    const int c = lane & 15;

    // Wt: async linear copy of F*LDKP*2 = 34816 B (padded source, padded dest)
    gload_lds_chunks((const char*)Wg, (char*)g.Wt, F * LDK * 2, wave, lane);

    for (int i = tid; i < 64 * (K / 4); i += 256) {
        int r = i >> 5, c4 = i & 31;
        int gr = rowb + r;
        float4 v = (gr < N) ? *(const float4*)(x + (size_t)gr * K + c4 * 4)
                            : make_float4(0.f, 0.f, 0.f, 0.f);
        h4 hv = { (_Float16)v.x, (_Float16)v.y, (_Float16)v.z, (_Float16)v.w };
        *(h4*)(g.As + r * LDK + c4 * 4) = hv;
    }
    __syncthreads();   // drains vmcnt (global_load_lds) + lgkmcnt (ds_write)

    f4 acc[NT];
#pragma unroll
    for (int nt = 0; nt < NT; nt++) acc[nt] = (f4)0.f;

    const _Float16* aw = g.As + (wave * 16 + c) * LDK + q * 8;
#pragma unroll
    for (int kt = 0; kt < 4; kt++) {
        h8 af = *(const h8*)(aw + kt * 32);
#pragma unroll
        for (int nt = 0; nt < NT; nt++) {
            h8 bf = *(const h8*)(g.Wt + (nt * 16 + c) * LDK + kt * 32 + q * 8);
            acc[nt] = __builtin_amdgcn_mfma_f32_16x16x32_f16(af, bf, acc[nt], 0, 0, 0);
        }
    }

    float asl[NT], adl[NT];
#pragma unroll
    for (int nt = 0; nt < NT; nt++) {
        asl[nt] = a_s[nt * 16 + c];
        adl[nt] = a_d[nt * 16 + c];
    }
    const int row0 = rowb + wave * 16 + q * 4;
#pragma unroll
    for (int r = 0; r < 4; r++) {
        int row = row0 + r;
        if (row < N) {
            float ps = 0.f, pd = 0.f;
#pragma unroll
            for (int nt = 0; nt < NT; nt++) {
                float v = acc[nt][r];
                hh[(size_t)row * F + nt * 16 + c] = (_Float16)v;
                ps += v * asl[nt];
                pd += v * adl[nt];
            }
#pragma unroll
            for (int off = 8; off >= 1; off >>= 1) {
                ps += __shfl_down(ps, off, 16);
                pd += __shfl_down(pd, off, 16);
            }
            if (c == 0) { alphaS[row] = ps; alphaD[row] = pd; }
        }
    }
}

// ---------------------------------------------------------------------------
// FAT A: blocks [0, gsplit) do gemm1 rows [0, gsplit*64); blocks
// [gsplit, gsplit+nbt) do bucket_scatter (LDS-sorted, coalesced staging).
// ---------------------------------------------------------------------------
__global__ __launch_bounds__(256) void fatA(
    const float* __restrict__ x, const _Float16* __restrict__ Wg,
    const float* __restrict__ a_s, const float* __restrict__ a_d,
    _Float16* __restrict__ hh, float* __restrict__ alphaS, float* __restrict__ alphaD,
    int N, int gsplit,
    const int* __restrict__ src, const int* __restrict__ dst,
    int* __restrict__ bfill, unsigned* __restrict__ staging, int cap, int E)
{
    __shared__ union {
        GemmLds g;
        struct {
            int lcnt[256]; int loff[256]; int gbase[256]; int ws[4];
            unsigned pairs[TILE]; unsigned char bkt[TILE];
        } s;
    } u;

    const int tid = threadIdx.x;

    if (blockIdx.x < (unsigned)gsplit) {
        gemm1_tile(u.g, tid, blockIdx.x * 64, x, Wg, a_s, a_d, hh, alphaS, alphaD, N);
    } else {
        // ================= bucket_scatter path =================
        const int base = (blockIdx.x - gsplit) * TILE;
        const int vt = min(TILE, E - base);

        u.s.lcnt[tid] = 0;
        __syncthreads();

        int d[TILE / 256], s[TILE / 256], r[TILE / 256];
#pragma unroll
        for (int j = 0; j < TILE / 256; j++) {
            int idx = base + j * 256 + tid;
            if (idx < E) {
                d[j] = dst[idx]; s[j] = src[idx];
                r[j] = atomicAdd(&u.s.lcnt[d[j] >> 8], 1);
            } else d[j] = -1;
        }
        __syncthreads();
        {
            int lane = tid & 63, wid = tid >> 6;
            int v = u.s.lcnt[tid];
            int incl = wave_iscan(v, lane);
            if (lane == 63) u.s.ws[wid] = incl;
            __syncthreads();
            int woff = 0;
            for (int w = 0; w < wid; w++) woff += u.s.ws[w];
            u.s.loff[tid] = woff + incl - v;
        }
        __syncthreads();
        {
            int c = u.s.lcnt[tid];
            if (c > 0) u.s.gbase[tid] = tid * cap + atomicAdd(&bfill[tid], c);
        }
        __syncthreads();
#pragma unroll
        for (int j = 0; j < TILE / 256; j++) {
            if (d[j] >= 0) {
                int b = d[j] >> 8;
                int slot = u.s.loff[b] + r[j];
                u.s.pairs[slot] = ((unsigned)d[j] << 16) | (unsigned)s[j];
                u.s.bkt[slot] = (unsigned char)b;
            }
        }
        __syncthreads();
        for (int slot = tid; slot < vt; slot += 256) {
            int b = u.s.bkt[slot];
            staging[u.s.gbase[b] + (slot - u.s.loff[b])] = u.s.pairs[slot];
        }
    }
}

// ---------------------------------------------------------------------------
// FAT B: blocks [0, ncsr) do bucket_to_csr (256-thread variant, hidden under
// the remaining GEMM blocks); blocks [ncsr, ...) do gemm1 rows [gsplit*64, N).
// ---------------------------------------------------------------------------
__global__ __launch_bounds__(256) void fatB(
    const float* __restrict__ x, const _Float16* __restrict__ Wg,
    const float* __restrict__ a_s, const float* __restrict__ a_d,
    _Float16* __restrict__ hh, float* __restrict__ alphaS, float* __restrict__ alphaD,
    int N, int gsplit, int ncsr,
    const unsigned* __restrict__ staging, const int* __restrict__ bfill,
    int* __restrict__ row_start, int* __restrict__ row_end,
    int* __restrict__ src_sorted, int cap)
{
    __shared__ union {
        GemmLds g;
        struct {
            unsigned lp[CSR_CAP];
            int lcnt[256]; int loff[256]; int lfill[256]; int ws[4];
        } c;
    } u;

    const int tid = threadIdx.x;

    if (blockIdx.x >= (unsigned)ncsr) {
        gemm1_tile(u.g, tid, (gsplit + blockIdx.x - ncsr) * 64,
                   x, Wg, a_s, a_d, hh, alphaS, alphaD, N);
    } else {
        // ================= bucket_to_csr path (256 threads) =================
        const int b = blockIdx.x;
        const int beg = b * cap;
        const int len = bfill[b];

        u.c.lcnt[tid] = 0;
        __syncthreads();
        for (int p = tid; p < len; p += 256) {
            unsigned v = staging[beg + p];
            u.c.lp[p] = v;  // len <= cap <= CSR_CAP
            atomicAdd(&u.c.lcnt[(v >> 16) & 255], 1);
        }
        __syncthreads();
        {
            int lane = tid & 63, wid = tid >> 6;
            int v = u.c.lcnt[tid];
            int incl = wave_iscan(v, lane);
            if (lane == 63) u.c.ws[wid] = incl;
            __syncthreads();
            int woff = 0;
            for (int w = 0; w < wid; w++) woff += u.c.ws[w];
            int excl = woff + incl - v;
            u.c.loff[tid] = excl;
            u.c.lfill[tid] = excl;
            int node = (b << 8) + tid;
            if (node < N) { row_start[node] = beg + excl; row_end[node] = beg + excl + v; }
        }
        __syncthreads();
        for (int p = tid; p < len; p += 256) {
            unsigned v = u.c.lp[p];
            int pos = atomicAdd(&u.c.lfill[(v >> 16) & 255], 1);
            src_sorted[beg + pos] = (int)(v & 0xFFFFu);
        }
    }
}

// ---------------------------------------------------------------------------
// MFMA GEMM + fused alpha dots (layer 2, fp16 input, padded fp16 W source).
// ---------------------------------------------------------------------------
template <int F, typename IT>
__global__ __launch_bounds__(256) void gemm_mfma(
    const IT* __restrict__ x, const _Float16* __restrict__ Wg,
    const float* __restrict__ a_s, const float* __restrict__ a_d,
    _Float16* __restrict__ hh, float* __restrict__ alphaS, float* __restrict__ alphaD,
    int N)
{
    constexpr int K = 128;
    constexpr int LDK = LDKP;
    constexpr int NT = F / 16;

    __shared__ _Float16 As[64 * LDK];
    __shared__ _Float16 Wt[F * LDK];

    const int tid = threadIdx.x;
    const int wave = tid >> 6;
    const int lane = tid & 63;
    const int q = lane >> 4;
    const int c = lane & 15;
    const int rowb = blockIdx.x * 64;

    // Wt: async linear copy of F*LDKP*2 bytes (17408 for F=64)
    gload_lds_chunks((const char*)Wg, (char*)Wt, F * LDK * 2, wave, lane);

    if constexpr (sizeof(IT) == 4) {
        for (int i = tid; i < 64 * (K / 4); i += 256) {
            int r = i >> 5, c4 = i & 31;
            int gr = rowb + r;
            float4 v = (gr < N) ? *(const float4*)((const float*)x + (size_t)gr * K + c4 * 4)
                                : make_float4(0.f, 0.f, 0.f, 0.f);
            h4 hv = { (_Float16)v.x, (_Float16)v.y, (_Float16)v.z, (_Float16)v.w };
            *(h4*)(As + r * LDK + c4 * 4) = hv;
        }
    } else {
        for (int i = tid; i < 64 * (K / 8); i += 256) {
            int r = i >> 4, c8 = i & 15;
            int gr = rowb + r;
            h8 v;
            if (gr < N) v = *(const h8*)((const _Float16*)x + (size_t)gr * K + c8 * 8);
            else        v = (h8)(_Float16)0.f;
            *(h8*)(As + r * LDK + c8 * 8) = v;
        }
    }
    __syncthreads();

    f4 acc[NT];
#pragma unroll
    for (int nt = 0; nt < NT; nt++) acc[nt] = (f4)0.f;

    const _Float16* aw = As + (wave * 16 + c) * LDK + q * 8;
#pragma unroll
    for (int kt = 0; kt < 4; kt++) {
        h8 af = *(const h8*)(aw + kt * 32);
#pragma unroll
        for (int nt = 0; nt < NT; nt++) {
            h8 bf = *(const h8*)(Wt + (nt * 16 + c) * LDK + kt * 32 + q * 8);
            acc[nt] = __builtin_amdgcn_mfma_f32_16x16x32_f16(af, bf, acc[nt], 0, 0, 0);
        }
    }

    float asl[NT], adl[NT];
#pragma unroll
    for (int nt = 0; nt < NT; nt++) {
        asl[nt] = a_s[nt * 16 + c];
        adl[nt] = a_d[nt * 16 + c];
    }
    const int row0 = rowb + wave * 16 + q * 4;
#pragma unroll
    for (int r = 0; r < 4; r++) {
        int row = row0 + r;
        if (row < N) {
            float ps = 0.f, pd = 0.f;
#pragma unroll
            for (int nt = 0; nt < NT; nt++) {
                float v = acc[nt][r];
                hh[(size_t)row * F + nt * 16 + c] = (_Float16)v;
                ps += v * asl[nt];
                pd += v * adl[nt];
            }
#pragma unroll
            for (int off = 8; off >= 1; off >>= 1) {
                ps += __shfl_down(ps, off, 16);
                pd += __shfl_down(pd, off, 16);
            }
            if (c == 0) { alphaS[row] = ps; alphaD[row] = pd; }
        }
    }
}

// ---------------------------------------------------------------------------
// Fused per-destination aggregation (round-1 verified): fp16 gather 16 B/lane,
// 4-stream edge unroll with index prefetch. Output fp16 or fp32.
// ---------------------------------------------------------------------------
template <int F, bool RELU, typename OT>
__global__ __launch_bounds__(256) void gat_aggregate(
    const int* __restrict__ row_start, const int* __restrict__ row_end,
    const int* __restrict__ src_sorted, const __half* __restrict__ hh,
    const float* __restrict__ aS, const float* __restrict__ aD,
    const float* __restrict__ bias, OT* __restrict__ out, int N)
{
    constexpr int LPE = F / 8;          // lanes per edge (16 or 8)
    constexpr int EPW = 64 / LPE;       // edge slots per wave (4 or 8)

    const int i = blockIdx.x * 4 + (threadIdx.x >> 6);
    if (i >= N) return;
    const int lane = threadIdx.x & 63;
    const int sub = lane / LPE;
    const int l = lane % LPE;

    const float adi = aD[i];
    const int start = row_start[i];
    const int end = row_end[i];

    float accA[8], accB[8];
#pragma unroll
    for (int q = 0; q < 8; q++) { accA[q] = 0.f; accB[q] = 0.f; }
    float denA = 0.f, denB = 0.f;

    int e = start + sub;
    int s0 = (e + 0 * EPW < end) ? src_sorted[e + 0 * EPW] : -1;
    int s1 = (e + 1 * EPW < end) ? src_sorted[e + 1 * EPW] : -1;
    int s2 = (e + 2 * EPW < end) ? src_sorted[e + 2 * EPW] : -1;
    int s3 = (e + 3 * EPW < end) ? src_sorted[e + 3 * EPW] : -1;

    while (s0 >= 0) {
        int eb = e + 4 * EPW;
        int n0 = (eb + 0 * EPW < end) ? src_sorted[eb + 0 * EPW] : -1;
        int n1 = (eb + 1 * EPW < end) ? src_sorted[eb + 1 * EPW] : -1;
        int n2 = (eb + 2 * EPW < end) ? src_sorted[eb + 2 * EPW] : -1;
        int n3 = (eb + 3 * EPW < end) ? src_sorted[eb + 3 * EPW] : -1;

        {
            float w = __expf(leaky(aS[s0] + adi));
            uint4 u = *(const uint4*)(hh + (size_t)s0 * F + l * 8);
            const __half2* hp = (const __half2*)&u;
#pragma unroll
            for (int q = 0; q < 4; q++) {
                float2 f = __half22float2(hp[q]);
                accA[q * 2] += w * f.x; accA[q * 2 + 1] += w * f.y;
            }
            denA += w;
        }
        if (s1 >= 0) {
            float w = __expf(leaky(aS[s1] + adi));
            uint4 u = *(const uint4*)(hh + (size_t)s1 * F + l * 8);
            const __half2* hp = (const __half2*)&u;
#pragma unroll
            for (int q = 0; q < 4; q++) {
                float2 f = __half22float2(hp[q]);
                accB[q * 2] += w * f.x; accB[q * 2 + 1] += w * f.y;
            }
            denB += w;
        }
        if (s2 >= 0) {
            float w = __expf(leaky(aS[s2] + adi));
            uint4 u = *(const uint4*)(hh + (size_t)s2 * F + l * 8);
            const __half2* hp = (const __half2*)&u;
#pragma unroll
            for (int q = 0; q < 4; q++) {
                float2 f = __half22float2(hp[q]);
                accA[q * 2] += w * f.x; accA[q * 2 + 1] += w * f.y;
            }
            denA += w;
        }
        if (s3 >= 0) {
            float w = __expf(leaky(aS[s3] + adi));
            uint4 u = *(const uint4*)(hh + (size_t)s3 * F + l * 8);
            const __half2* hp = (const __half2*)&u;
#pragma unroll
            for (int q = 0; q < 4; q++) {
                float2 f = __half22float2(hp[q]);
                accB[q * 2] += w * f.x; accB[q * 2 + 1] += w * f.y;
            }
            denB += w;
        }
        e = eb;
        s0 = n0; s1 = n1; s2 = n2; s3 = n3;
    }

    float acc[8];
#pragma unroll
    for (int q = 0; q < 8; q++) acc[q] = accA[q] + accB[q];
    float denom = denA + denB;

#pragma unroll
    for (int off = 32; off >= LPE; off >>= 1) {
#pragma unroll
        for (int q = 0; q < 8; q++) acc[q] += __shfl_down(acc[q], off);
        denom += __shfl_down(denom, off);
    }

    if (sub == 0) {
        float wsf = __expf(leaky(aS[i] + adi));
        uint4 u = *(const uint4*)(hh + (size_t)i * F + l * 8);
        const __half2* hp = (const __half2*)&u;
        float inv = 1.f / (denom + wsf);
        float4 b0 = *(const float4*)(bias + l * 8);
        float4 b1 = *(const float4*)(bias + l * 8 + 4);
        float o[8];
#pragma unroll
        for (int q = 0; q < 4; q++) {
            float2 f = __half22float2(hp[q]);
            o[q * 2]     = (acc[q * 2]     + wsf * f.x) * inv;
            o[q * 2 + 1] = (acc[q * 2 + 1] + wsf * f.y) * inv;
        }
        o[0] += b0.x; o[1] += b0.y; o[2] += b0.z; o[3] += b0.w;
        o[4] += b1.x; o[5] += b1.y; o[6] += b1.z; o[7] += b1.w;
        if (RELU) {
#pragma unroll
            for (int q = 0; q < 8; q++) o[q] = fmaxf(o[q], 0.f);
        }
        if constexpr (sizeof(OT) == 2) {
            __half2 qh[4];
            qh[0] = __floats2half2_rn(o[0], o[1]);
            qh[1] = __floats2half2_rn(o[2], o[3]);
            qh[2] = __floats2half2_rn(o[4], o[5]);
            qh[3] = __floats2half2_rn(o[6], o[7]);
            *(uint4*)((__half*)out + (size_t)i * F + l * 8) = *(uint4*)qh;
        } else {
            *(float4*)((float*)out + (size_t)i * F + l * 8)     = make_float4(o[0], o[1], o[2], o[3]);
            *(float4*)((float*)out + (size_t)i * F + l * 8 + 4) = make_float4(o[4], o[5], o[6], o[7]);
        }
    }
}

extern "C" void kernel_launch(void* const* d_in, const int* in_sizes, int n_in,
                              void* d_out, int out_size, void* d_ws, size_t ws_size,
                              hipStream_t stream)
{
    const float* x   = (const float*)d_in[0];
    const int*   ei  = (const int*)d_in[1];
    const float* W1  = (const float*)d_in[2];
    const float* aS1 = (const float*)d_in[3];
    const float* aD1 = (const float*)d_in[4];
    const float* b1  = (const float*)d_in[5];
    const float* W2  = (const float*)d_in[6];
    const float* aS2 = (const float*)d_in[7];
    const float* aD2 = (const float*)d_in[8];
    const float* b2  = (const float*)d_in[9];

    const int K = 128, F1 = 128, F2 = 64;
    const int N = in_sizes[0] / K;   // 50000 (< 65536: packed u32 staging valid)
    const int E = in_sizes[1] / 2;
    const int* src = ei;
    const int* dst = ei + E;

    const int Np = (N + 4) & ~3;
    const int NB = (N + 255) >> 8;
    const int nbt = (E + TILE - 1) / TILE;
    const int nblk_gemm = (N + 63) / 64;
    const int gsplit = (nblk_gemm * 5) / 8;        // gemm blocks in fatA
    int cap = (((E / NB) * 3) / 2 + 255) & ~255;   // 1.5x mean, 256-aligned
    if (cap > CSR_CAP) cap = CSR_CAP;

    char* wsb = (char*)d_ws;
    int* bfill        = (int*)wsb;      wsb += 256 * 4;                       // zeroed by prep
    _Float16* W1t     = (_Float16*)wsb; wsb += 128 * LDKP * 2;                // fp16 W1^T padded
    _Float16* W2t     = (_Float16*)wsb; wsb += 64 * LDKP * 2;                 // fp16 W2^T padded
    int* row_start    = (int*)wsb;      wsb += (size_t)Np * 4;
    int* row_end      = (int*)wsb;      wsb += (size_t)Np * 4;
    unsigned* staging = (unsigned*)wsb; wsb += (size_t)NB * CSR_CAP * 4;
    int* src_sorted   = (int*)wsb;      wsb += (size_t)NB * CSR_CAP * 4;
    _Float16* hh1     = (_Float16*)wsb; wsb += (size_t)N * F1 * 2;
    _Float16* x2h     = (_Float16*)wsb; wsb += (size_t)N * F1 * 2;
    _Float16* hh2     = (_Float16*)wsb; wsb += (size_t)N * F2 * 2;
    float* as_        = (float*)wsb;    wsb += (size_t)Np * 4;
    float* ad_        = (float*)wsb;    wsb += (size_t)Np * 4;
    float* as2_       = (float*)wsb;    wsb += (size_t)Np * 4;
    float* ad2_       = (float*)wsb;    wsb += (size_t)Np * 4;

    dim3 blk(256);

    // ---- prep: zero bfill + padded fp16 W transposes ----
    prep<<<dim3(12), blk, 0, stream>>>(W1, W2, W1t, W2t, bfill);

    // ---- fat A: gemm1 rows [0, gsplit*64) overlapped with bucket_scatter ----
    fatA<<<dim3(gsplit + nbt), blk, 0, stream>>>(
        x, W1t, aS1, aD1, hh1, as_, ad_, N, gsplit,
        src, dst, bfill, staging, cap, E);

    // ---- fat B: bucket_to_csr hidden under gemm1 rows [gsplit*64, N) ----
    fatB<<<dim3(NB + (nblk_gemm - gsplit)), blk, 0, stream>>>(
        x, W1t, aS1, aD1, hh1, as_, ad_, N, gsplit, NB,
        staging, bfill, row_start, row_end, src_sorted, cap);

    // ---- layer-1 aggregate -> fp16 x2 ----
    gat_aggregate<F1, true, __half><<<dim3((N + 3) / 4), blk, 0, stream>>>(
        row_start, row_end, src_sorted, (const __half*)hh1, as_, ad_, b1,
        (__half*)x2h, N);

    // ---- layer-2 GEMM (MFMA, fp16 input) ----
    gemm_mfma<F2, _Float16><<<dim3((N + 63) / 64), blk, 0, stream>>>(
        x2h, W2t, aS2, aD2, hh2, as2_, ad2_, N);

    // ---- layer-2 aggregate -> d_out ----
    gat_aggregate<F2, false, float><<<dim3((N + 3) / 4), blk, 0, stream>>>(
        row_start, row_end, src_sorted, (const __half*)hh2, as2_, ad2_, b2,
        (float*)d_out, N);
}